// Round 9
// baseline (138.001 us; speedup 1.0000x reference)
//
#include <hip/hip_runtime.h>
#include <hip/hip_bf16.h>

#define D 64
#define LOGB 7            // 128 nodes per bin-bucket (binning kernels)
#define BNODES 128
#define SUBN 64           // nodes per k_bucket3 block (half a bin-bucket)
#define CHUNK 2048
#define TN 64             // nodes per k_transform3 block

__device__ __forceinline__ float bf2f(ushort u) {
    unsigned v = ((unsigned)u) << 16;
    return __uint_as_float(v);
}
__device__ __forceinline__ float blo(unsigned u) { return __uint_as_float(u << 16); }
__device__ __forceinline__ float bhi(unsigned u) { return __uint_as_float(u & 0xffff0000u); }
__device__ __forceinline__ ushort f2bfr(float x) {
    __hip_bfloat16 hb = __float2bfloat16(x);     // RNE
    return *reinterpret_cast<ushort*>(&hb);
}

// ---------------- transform: g = bf16(feat @ W), tiled GEMM; also zeroes bcnt ----------------
// Block = 256 threads, 64 nodes. ft is k-major (transposed feat tile) so a
// thread's 4 node-features at step k are one float4; Ws row-major. Thread
// (nq=t>>4, cq=t&15) computes the 4-node x 4-col micro-tile
// nodes n0+4nq..+3, cols 4cq..4cq+3: per k = 2 ds_read_b128 + 16 fma.

__global__ __launch_bounds__(256) void k_transform3(
    const float* __restrict__ feat, const float* __restrict__ W,
    ushort* __restrict__ g, int n_nodes, int* __restrict__ bcnt, int nbkt)
{
    int gt = blockIdx.x * 256 + threadIdx.x;
    if (gt < nbkt) bcnt[gt] = 0;

    __shared__ float ft[D][TN];   // [k][node], 16 KB
    __shared__ float Ws[D][D];    // [k][j],    16 KB

    int t = threadIdx.x;
    int n0 = blockIdx.x * TN;

    {   // stage W (4096 floats = 1024 float4), coalesced
        const float4* W4 = (const float4*)W;
        float4* Ws4 = (float4*)&Ws[0][0];
        #pragma unroll
        for (int i = 0; i < 4; ++i) Ws4[t + i * 256] = W4[t + i * 256];
    }

    {   // stage feat tile transposed: 64 rows x 16 float4, coalesced loads
        const float4* f4 = (const float4*)feat;
        #pragma unroll
        for (int it = 0; it < 4; ++it) {
            int i = it * 256 + t;
            int r = i >> 4, c = i & 15;
            int node = n0 + r;
            float4 v = (node < n_nodes) ? f4[(size_t)node * 16 + c]
                                        : make_float4(0.f, 0.f, 0.f, 0.f);
            ft[4 * c + 0][r] = v.x;
            ft[4 * c + 1][r] = v.y;
            ft[4 * c + 2][r] = v.z;
            ft[4 * c + 3][r] = v.w;
        }
    }
    __syncthreads();

    int nq = t >> 4;              // 0..15 -> nodes 4nq..4nq+3
    int cq = t & 15;              // 0..15 -> cols  4cq..4cq+3
    int n4 = nq * 4, c4 = cq * 4;

    float4 a0 = make_float4(0.f, 0.f, 0.f, 0.f);
    float4 a1 = a0, a2 = a0, a3 = a0;

    #pragma unroll 16
    for (int k = 0; k < D; ++k) {
        float4 fv = *reinterpret_cast<const float4*>(&ft[k][n4]);
        float4 wv = *reinterpret_cast<const float4*>(&Ws[k][c4]);
        a0.x = fmaf(fv.x, wv.x, a0.x); a0.y = fmaf(fv.x, wv.y, a0.y);
        a0.z = fmaf(fv.x, wv.z, a0.z); a0.w = fmaf(fv.x, wv.w, a0.w);
        a1.x = fmaf(fv.y, wv.x, a1.x); a1.y = fmaf(fv.y, wv.y, a1.y);
        a1.z = fmaf(fv.y, wv.z, a1.z); a1.w = fmaf(fv.y, wv.w, a1.w);
        a2.x = fmaf(fv.z, wv.x, a2.x); a2.y = fmaf(fv.z, wv.y, a2.y);
        a2.z = fmaf(fv.z, wv.z, a2.z); a2.w = fmaf(fv.z, wv.w, a2.w);
        a3.x = fmaf(fv.w, wv.x, a3.x); a3.y = fmaf(fv.w, wv.y, a3.y);
        a3.z = fmaf(fv.w, wv.z, a3.z); a3.w = fmaf(fv.w, wv.w, a3.w);
    }

    float4 accs[4] = {a0, a1, a2, a3};
    #pragma unroll
    for (int i = 0; i < 4; ++i) {
        int node = n0 + n4 + i;
        if (node < n_nodes) {
            ushort4 o;
            o.x = f2bfr(accs[i].x);
            o.y = f2bfr(accs[i].y);
            o.z = f2bfr(accs[i].z);
            o.w = f2bfr(accs[i].w);
            *reinterpret_cast<ushort4*>(g + (size_t)node * D + c4) = o;
        }
    }
}

// ---------------- bucket binning ----------------

__global__ __launch_bounds__(256) void k_bin_count(
    const int* __restrict__ dst, int* __restrict__ cnt, int n_edges, int nbkt)
{
    __shared__ int sc[1024];
    int t = threadIdx.x;
    for (int i = t; i < 1024; i += 256) sc[i] = 0;
    __syncthreads();
    int n4 = n_edges >> 2;
    const int4* d4 = (const int4*)dst;
    int stride = gridDim.x * 256;
    for (int i = blockIdx.x * 256 + t; i < n4; i += stride) {
        int4 d = d4[i];
        atomicAdd(&sc[d.x >> LOGB], 1);
        atomicAdd(&sc[d.y >> LOGB], 1);
        atomicAdd(&sc[d.z >> LOGB], 1);
        atomicAdd(&sc[d.w >> LOGB], 1);
    }
    if (blockIdx.x == 0 && t == 0)
        for (int e = n4 << 2; e < n_edges; ++e) atomicAdd(&cnt[dst[e] >> LOGB], 1);
    __syncthreads();
    for (int i = t; i < nbkt; i += 256) {
        int c = sc[i];
        if (c) atomicAdd(&cnt[i], c);
    }
}

__global__ __launch_bounds__(1024) void k_bin_scan(
    const int* __restrict__ cnt, int* __restrict__ base,
    int* __restrict__ cursor, int nbkt)
{
    int t = threadIdx.x;
    int v = (t < nbkt) ? cnt[t] : 0;
    int lane = t & 63;
    int incl = v;
    #pragma unroll
    for (int o = 1; o < 64; o <<= 1) {
        int u = __shfl_up(incl, o, 64);
        if (lane >= o) incl += u;
    }
    __shared__ int wtot[16];
    if (lane == 63) wtot[t >> 6] = incl;
    __syncthreads();
    int wpre = 0;
    int w = t >> 6;
    for (int i = 0; i < w; ++i) wpre += wtot[i];
    int excl = wpre + incl - v;
    if (t < nbkt) { base[t] = excl; cursor[t] = excl; }
    if (t == nbkt - 1) base[nbkt] = excl + v;
}

__global__ __launch_bounds__(256) void k_bin_scatter(
    const int* __restrict__ src, const int* __restrict__ dst,
    int* __restrict__ cursor, unsigned* __restrict__ packed,
    int n_edges, int sbits)
{
    __shared__ int s_cnt[1024];
    __shared__ int s_base[1024];
    __shared__ int s_gb[1024];
    __shared__ int wtot[4];
    __shared__ unsigned s_stage[4096];
    __shared__ int s_addr[4096];

    int t = threadIdx.x;
    int chbase = blockIdx.x * 4096;
    int count = n_edges - chbase;
    if (count > 4096) count = 4096;

    for (int i = t; i < 1024; i += 256) s_cnt[i] = 0;
    __syncthreads();

    #pragma unroll
    for (int k = 0; k < 16; ++k) {
        int i = t + k * 256;
        if (i < count) atomicAdd(&s_cnt[dst[chbase + i] >> LOGB], 1);
    }
    __syncthreads();

    int b4 = t * 4;
    int v0 = s_cnt[b4], v1 = s_cnt[b4 + 1], v2 = s_cnt[b4 + 2], v3 = s_cnt[b4 + 3];
    int ssum = v0 + v1 + v2 + v3;
    int lane = t & 63;
    int incl = ssum;
    #pragma unroll
    for (int o = 1; o < 64; o <<= 1) {
        int u = __shfl_up(incl, o, 64);
        if (lane >= o) incl += u;
    }
    if (lane == 63) wtot[t >> 6] = incl;
    __syncthreads();
    int wpre = 0;
    int w = t >> 6;
    for (int i = 0; i < w; ++i) wpre += wtot[i];
    int excl = wpre + incl - ssum;
    s_base[b4]     = excl;
    s_base[b4 + 1] = excl + v0;
    s_base[b4 + 2] = excl + v0 + v1;
    s_base[b4 + 3] = excl + v0 + v1 + v2;
    __syncthreads();

    for (int i = t; i < 1024; i += 256) {
        int c = s_cnt[i];
        s_gb[i] = c ? atomicAdd(&cursor[i], c) : 0;
    }
    __syncthreads();
    for (int i = t; i < 1024; i += 256) s_cnt[i] = s_base[i];
    __syncthreads();

    #pragma unroll
    for (int k = 0; k < 16; ++k) {
        int i = t + k * 256;
        if (i < count) {
            int e = chbase + i;
            int d = dst[e];
            int s = src[e];
            int bkt = d >> LOGB;
            int pos = atomicAdd(&s_cnt[bkt], 1);
            s_stage[pos] = ((unsigned)(d & (BNODES - 1)) << sbits) | (unsigned)s;
            s_addr[pos]  = s_gb[bkt] + (pos - s_base[bkt]);
        }
    }
    __syncthreads();

    #pragma unroll
    for (int k = 0; k < 16; ++k) {
        int i = t + k * 256;
        if (i < count) packed[s_addr[i]] = s_stage[i];
    }
}

// ---------------- per-sub-bucket: in-LDS sort + quarter-wave segment-sum ----------------

__global__ __launch_bounds__(256) void k_bucket3(
    const ushort* __restrict__ g,
    const float* __restrict__ bias,
    const int* __restrict__ base,
    const unsigned* __restrict__ packed,
    float* __restrict__ out,
    int n_nodes, int sbits)
{
    __shared__ unsigned s_rec[CHUNK];     // 8 KB
    __shared__ int s_cnt[SUBN];
    __shared__ int s_off[SUBN + 1];

    int t = threadIdx.x;
    int lane = t & 63;
    int wid  = t >> 6;                    // 0..3
    int q = lane >> 4;                    // quarter-group 0..3
    int m = lane & 15;                    // sub-lane: features 4m..4m+3
    int bkt = blockIdx.x >> 1;
    int sub = blockIdx.x & 1;
    int gb = base[bkt], ge = base[bkt + 1];
    unsigned smask = (1u << sbits) - 1u;

    float4 acc[16];
    int degv[16];
    #pragma unroll
    for (int k = 0; k < 16; ++k) {
        acc[k] = make_float4(0.f, 0.f, 0.f, 0.f);
        degv[k] = 0;
    }

    for (int cb = gb; cb < ge; cb += CHUNK) {
        int cnt = ge - cb;
        if (cnt > CHUNK) cnt = CHUNK;

        __syncthreads();
        if (t < SUBN) s_cnt[t] = 0;
        __syncthreads();

        for (int i = t; i < cnt; i += 256) {
            unsigned v = packed[cb + i];
            unsigned key = v >> sbits;
            if ((int)(key >> 6) == sub) atomicAdd(&s_cnt[key & 63], 1);
        }
        __syncthreads();

        if (t < 64) {
            int v = s_cnt[t];
            int incl = v;
            #pragma unroll
            for (int o = 1; o < 64; o <<= 1) {
                int u = __shfl_up(incl, o, 64);
                if (t >= o) incl += u;
            }
            int excl = incl - v;
            s_off[t] = excl;
            s_cnt[t] = excl;
            if (t == 63) s_off[64] = incl;
        }
        __syncthreads();

        for (int i = t; i < cnt; i += 256) {
            unsigned v = packed[cb + i];
            unsigned key = v >> sbits;
            if ((int)(key >> 6) == sub) {
                int pos = atomicAdd(&s_cnt[key & 63], 1);
                s_rec[pos] = v;
            }
        }
        __syncthreads();

        #pragma unroll
        for (int k = 0; k < 16; ++k) {
            int r = wid * 16 + k;
            int beg = s_off[r], end = s_off[r + 1];
            float4 a = acc[k];
            for (int i = beg; i < end; i += 8) {
                int i0 = i + q, i1 = i + q + 4;
                bool p0 = i0 < end, p1 = i1 < end;
                unsigned r0 = s_rec[p0 ? i0 : beg];
                unsigned r1 = s_rec[p1 ? i1 : beg];
                int s0 = (int)(r0 & smask);
                int s1 = (int)(r1 & smask);
                uint2 u0 = *reinterpret_cast<const uint2*>(g + s0 * D + 4 * m);
                uint2 u1 = *reinterpret_cast<const uint2*>(g + s1 * D + 4 * m);
                a.x += p0 ? blo(u0.x) : 0.0f;
                a.y += p0 ? bhi(u0.x) : 0.0f;
                a.z += p0 ? blo(u0.y) : 0.0f;
                a.w += p0 ? bhi(u0.y) : 0.0f;
                a.x += p1 ? blo(u1.x) : 0.0f;
                a.y += p1 ? bhi(u1.x) : 0.0f;
                a.z += p1 ? blo(u1.y) : 0.0f;
                a.w += p1 ? bhi(u1.y) : 0.0f;
            }
            acc[k] = a;
            degv[k] += end - beg;
        }
    }

    float4 bj = *reinterpret_cast<const float4*>(bias + 4 * m);
    int n0 = (bkt << LOGB) + sub * SUBN;
    #pragma unroll
    for (int k = 0; k < 16; ++k) {
        float4 v = acc[k];
        v.x += __shfl_xor(v.x, 16, 64);
        v.y += __shfl_xor(v.y, 16, 64);
        v.z += __shfl_xor(v.z, 16, 64);
        v.w += __shfl_xor(v.w, 16, 64);
        v.x += __shfl_xor(v.x, 32, 64);
        v.y += __shfl_xor(v.y, 32, 64);
        v.z += __shfl_xor(v.z, 32, 64);
        v.w += __shfl_xor(v.w, 32, 64);
        if ((k & 3) == q) {
            int node = n0 + wid * 16 + k;
            if (node < n_nodes) {
                int dgt = degv[k];
                float4 res;
                if (dgt > 0) {
                    float inv = 1.0f / (float)dgt;
                    res = make_float4(v.x * inv, v.y * inv, v.z * inv, v.w * inv);
                } else {
                    uint2 u = *reinterpret_cast<const uint2*>(g + node * D + 4 * m);
                    res = make_float4(blo(u.x), bhi(u.x), blo(u.y), bhi(u.y));
                }
                res.x = fmaxf(res.x + bj.x, 0.0f);
                res.y = fmaxf(res.y + bj.y, 0.0f);
                res.z = fmaxf(res.z + bj.z, 0.0f);
                res.w = fmaxf(res.w + bj.w, 0.0f);
                *reinterpret_cast<float4*>(out + node * D + 4 * m) = res;
            }
        }
    }
}

// ---------------- fallback: R3 CSR path ----------------

__global__ __launch_bounds__(256) void k_hist(
    const int* __restrict__ dst, int* __restrict__ cnt, int n_edges)
{
    int n4 = n_edges >> 2;
    const int4* d4 = (const int4*)dst;
    int stride = gridDim.x * blockDim.x;
    for (int i = blockIdx.x * blockDim.x + threadIdx.x; i < n4; i += stride) {
        int4 d = d4[i];
        atomicAdd(&cnt[d.x], 1); atomicAdd(&cnt[d.y], 1);
        atomicAdd(&cnt[d.z], 1); atomicAdd(&cnt[d.w], 1);
    }
    if (blockIdx.x == 0 && threadIdx.x == 0)
        for (int e = n4 << 2; e < n_edges; ++e) atomicAdd(&cnt[dst[e]], 1);
}

__global__ __launch_bounds__(256) void k_scan1(
    const int* __restrict__ cnt, int* __restrict__ off,
    int* __restrict__ bsum, int n)
{
    int t = threadIdx.x, b = blockIdx.x;
    int base = b * 1024 + t * 4;
    int v0 = (base + 0 < n) ? cnt[base + 0] : 0;
    int v1 = (base + 1 < n) ? cnt[base + 1] : 0;
    int v2 = (base + 2 < n) ? cnt[base + 2] : 0;
    int v3 = (base + 3 < n) ? cnt[base + 3] : 0;
    int s = v0 + v1 + v2 + v3;
    int lane = t & 63;
    int incl = s;
    #pragma unroll
    for (int o = 1; o < 64; o <<= 1) {
        int u = __shfl_up(incl, o, 64);
        if (lane >= o) incl += u;
    }
    __shared__ int wtot[4];
    if (lane == 63) wtot[t >> 6] = incl;
    __syncthreads();
    int w = t >> 6;
    int wpre = 0;
    for (int i = 0; i < w; ++i) wpre += wtot[i];
    int excl = wpre + incl - s;
    int p0 = excl + v0, p1 = p0 + v1, p2 = p1 + v2, p3 = p2 + v3;
    if (base + 0 < n) off[base + 1] = p0;
    if (base + 1 < n) off[base + 2] = p1;
    if (base + 2 < n) off[base + 3] = p2;
    if (base + 3 < n) off[base + 4] = p3;
    if (t == 255) bsum[b] = wpre + incl;
}

__global__ __launch_bounds__(128) void k_scan2(int* __restrict__ bsum, int nb)
{
    int t = threadIdx.x;
    int v = (t < nb) ? bsum[t] : 0;
    int lane = t & 63;
    int incl = v;
    #pragma unroll
    for (int o = 1; o < 64; o <<= 1) {
        int u = __shfl_up(incl, o, 64);
        if (lane >= o) incl += u;
    }
    __shared__ int wt[2];
    if (lane == 63) wt[t >> 6] = incl;
    __syncthreads();
    int add = (t >> 6) ? wt[0] : 0;
    if (t < nb) bsum[t] = add + incl - v;
}

__global__ __launch_bounds__(256) void k_scan3(
    int* __restrict__ off, int* __restrict__ cursor,
    const int* __restrict__ bsum, int n)
{
    int t = threadIdx.x, b = blockIdx.x;
    int base = b * 1024 + t * 4;
    int add = bsum[b];
    #pragma unroll
    for (int i = 0; i < 4; ++i) {
        int idx = base + i;
        if (idx < n) {
            int v = off[idx + 1] + add;
            off[idx + 1] = v;
            if (idx + 1 < n) cursor[idx + 1] = v;
        }
    }
    if (b == 0 && t == 0) { off[0] = 0; cursor[0] = 0; }
}

__global__ __launch_bounds__(256) void k_scatter_csr(
    const int* __restrict__ src, const int* __restrict__ dst,
    int* __restrict__ cursor, int* __restrict__ csr, int n_edges)
{
    int n4 = n_edges >> 2;
    const int4* s4 = (const int4*)src;
    const int4* d4 = (const int4*)dst;
    int stride = gridDim.x * blockDim.x;
    for (int i = blockIdx.x * blockDim.x + threadIdx.x; i < n4; i += stride) {
        int4 s = s4[i];
        int4 d = d4[i];
        csr[atomicAdd(&cursor[d.x], 1)] = s.x;
        csr[atomicAdd(&cursor[d.y], 1)] = s.y;
        csr[atomicAdd(&cursor[d.z], 1)] = s.z;
        csr[atomicAdd(&cursor[d.w], 1)] = s.w;
    }
    if (blockIdx.x == 0 && threadIdx.x == 0)
        for (int e = n4 << 2; e < n_edges; ++e)
            csr[atomicAdd(&cursor[dst[e]], 1)] = src[e];
}

__global__ __launch_bounds__(256) void k_node(
    const float* __restrict__ feat, const float* __restrict__ W,
    const float* __restrict__ bias, const int* __restrict__ off,
    const int* __restrict__ csr, float* __restrict__ out, int n_nodes)
{
    __shared__ float Wl[D * D];
    int tid = threadIdx.x;
    for (int i = tid; i < D * D; i += 256) Wl[i] = W[i];
    __syncthreads();
    int lane = tid & 63, wid = tid >> 6;
    float bj = bias[lane];
    int nwaves = gridDim.x * 4;
    for (int n = blockIdx.x * 4 + wid; n < n_nodes; n += nwaves) {
        int beg = off[n], end = off[n + 1];
        float acc = 0.0f;
        int i = beg;
        for (; i + 4 <= end; i += 4) {
            int s0 = csr[i], s1 = csr[i + 1], s2 = csr[i + 2], s3 = csr[i + 3];
            acc += feat[s0 * D + lane] + feat[s1 * D + lane]
                 + feat[s2 * D + lane] + feat[s3 * D + lane];
        }
        for (; i < end; ++i) acc += feat[csr[i] * D + lane];
        int dg = end - beg;
        float h = (dg > 0) ? (acc / (float)dg) : feat[n * D + lane];
        float o = bj;
        #pragma unroll
        for (int k = 0; k < D; ++k)
            o = fmaf(__shfl(h, k, 64), Wl[k * D + lane], o);
        out[n * D + lane] = fmaxf(o, 0.0f);
    }
}

// ---------------- host ----------------

extern "C" void kernel_launch(void* const* d_in, const int* in_sizes, int n_in,
                              void* d_out, int out_size, void* d_ws, size_t ws_size,
                              hipStream_t stream)
{
    const float* feat = (const float*)d_in[0];
    const int*   src  = (const int*)d_in[1];
    const int*   dst  = (const int*)d_in[2];
    const float* W    = (const float*)d_in[3];
    const float* b    = (const float*)d_in[4];
    float* out = (float*)d_out;

    int n_nodes = in_sizes[0] / D;
    int n_edges = in_sizes[1];
    int nbkt = (n_nodes + BNODES - 1) >> LOGB;

    int sbits = 1;
    while ((1 << sbits) < n_nodes && sbits < 26) sbits++;

    // ws layout: base[nbkt+1] | cnt[nbkt] | cursor[nbkt] | packed[E] u32 | g[N*D] u16
    size_t base_off   = 0;
    size_t cnt_off    = (((size_t)(nbkt + 1) * 4) + 63) & ~(size_t)63;
    size_t cursor_off = (cnt_off + (size_t)nbkt * 4 + 63) & ~(size_t)63;
    size_t packed_off = (cursor_off + (size_t)nbkt * 4 + 63) & ~(size_t)63;
    size_t g_off      = (packed_off + (size_t)n_edges * 4 + 63) & ~(size_t)63;
    size_t need_new   = g_off + (size_t)n_nodes * D * 2;

    bool new_ok = (ws_size >= need_new) && (nbkt <= 1024) &&
                  (sbits + LOGB <= 32) && ((1 << sbits) >= n_nodes);

    if (new_ok) {
        char* ws = (char*)d_ws;
        int* bbase   = (int*)(ws + base_off);
        int* bcnt    = (int*)(ws + cnt_off);
        int* bcursor = (int*)(ws + cursor_off);
        unsigned* packed = (unsigned*)(ws + packed_off);
        ushort* g    = (ushort*)(ws + g_off);

        int tblk = (n_nodes + TN - 1) / TN;
        k_transform3<<<tblk, 256, 0, stream>>>(feat, W, g, n_nodes, bcnt, nbkt);
        k_bin_count<<<512, 256, 0, stream>>>(dst, bcnt, n_edges, nbkt);
        k_bin_scan<<<1, 1024, 0, stream>>>(bcnt, bbase, bcursor, nbkt);
        int nblk = (n_edges + 4095) / 4096;
        k_bin_scatter<<<nblk, 256, 0, stream>>>(src, dst, bcursor, packed,
                                                n_edges, sbits);
        k_bucket3<<<nbkt * 2, 256, 0, stream>>>(g, b, bbase, packed, out,
                                                n_nodes, sbits);
    } else {
        // R3 CSR fallback
        int nb = (n_nodes + 1023) / 1024;
        size_t c_off  = 0;
        size_t o_off  = (((size_t)n_nodes * 4) + 63) & ~(size_t)63;
        size_t bs_off = (o_off + ((size_t)n_nodes + 1) * 4 + 63) & ~(size_t)63;
        size_t cs_off = (bs_off + 128 * 4 + 63) & ~(size_t)63;
        char* ws = (char*)d_ws;
        int* cnt  = (int*)(ws + c_off);
        int* off  = (int*)(ws + o_off);
        int* bsum = (int*)(ws + bs_off);
        int* csr  = (int*)(ws + cs_off);

        hipMemsetAsync(cnt, 0, (size_t)n_nodes * 4, stream);
        k_hist<<<2048, 256, 0, stream>>>(dst, cnt, n_edges);
        k_scan1<<<nb, 256, 0, stream>>>(cnt, off, bsum, n_nodes);
        k_scan2<<<1, 128, 0, stream>>>(bsum, nb);
        k_scan3<<<nb, 256, 0, stream>>>(off, cnt, bsum, n_nodes);
        k_scatter_csr<<<2048, 256, 0, stream>>>(src, dst, cnt, csr, n_edges);
        k_node<<<2048, 256, 0, stream>>>(feat, W, b, off, csr, out, n_nodes);
    }
}

// Round 10
// 132.621 us; speedup vs baseline: 1.0406x; 1.0406x over previous
//
#include <hip/hip_runtime.h>
#include <hip/hip_bf16.h>

#define D 64
#define LOGB 7            // 128 nodes per bin-bucket (binning kernels)
#define BNODES 128
#define SUBN 32           // nodes per k_bucket4 block (quarter bin-bucket)
#define CHUNK 1024
#define TN 64             // nodes per k_transform3 block

__device__ __forceinline__ float bf2f(ushort u) {
    unsigned v = ((unsigned)u) << 16;
    return __uint_as_float(v);
}
__device__ __forceinline__ float blo(unsigned u) { return __uint_as_float(u << 16); }
__device__ __forceinline__ float bhi(unsigned u) { return __uint_as_float(u & 0xffff0000u); }
__device__ __forceinline__ ushort f2bfr(float x) {
    __hip_bfloat16 hb = __float2bfloat16(x);     // RNE
    return *reinterpret_cast<ushort*>(&hb);
}

// ---------------- transform: g = bf16(feat @ W), tiled GEMM; also zeroes bcnt ----------------

__global__ __launch_bounds__(256) void k_transform3(
    const float* __restrict__ feat, const float* __restrict__ W,
    ushort* __restrict__ g, int n_nodes, int* __restrict__ bcnt, int nbkt)
{
    int gt = blockIdx.x * 256 + threadIdx.x;
    if (gt < nbkt) bcnt[gt] = 0;

    __shared__ float ft[D][TN];   // [k][node], 16 KB
    __shared__ float Ws[D][D];    // [k][j],    16 KB

    int t = threadIdx.x;
    int n0 = blockIdx.x * TN;

    {   // stage W (4096 floats = 1024 float4), coalesced
        const float4* W4 = (const float4*)W;
        float4* Ws4 = (float4*)&Ws[0][0];
        #pragma unroll
        for (int i = 0; i < 4; ++i) Ws4[t + i * 256] = W4[t + i * 256];
    }

    {   // stage feat tile transposed: 64 rows x 16 float4, coalesced loads
        const float4* f4 = (const float4*)feat;
        #pragma unroll
        for (int it = 0; it < 4; ++it) {
            int i = it * 256 + t;
            int r = i >> 4, c = i & 15;
            int node = n0 + r;
            float4 v = (node < n_nodes) ? f4[(size_t)node * 16 + c]
                                        : make_float4(0.f, 0.f, 0.f, 0.f);
            ft[4 * c + 0][r] = v.x;
            ft[4 * c + 1][r] = v.y;
            ft[4 * c + 2][r] = v.z;
            ft[4 * c + 3][r] = v.w;
        }
    }
    __syncthreads();

    int nq = t >> 4;              // 0..15 -> nodes 4nq..4nq+3
    int cq = t & 15;              // 0..15 -> cols  4cq..4cq+3
    int n4 = nq * 4, c4 = cq * 4;

    float4 a0 = make_float4(0.f, 0.f, 0.f, 0.f);
    float4 a1 = a0, a2 = a0, a3 = a0;

    #pragma unroll 16
    for (int k = 0; k < D; ++k) {
        float4 fv = *reinterpret_cast<const float4*>(&ft[k][n4]);
        float4 wv = *reinterpret_cast<const float4*>(&Ws[k][c4]);
        a0.x = fmaf(fv.x, wv.x, a0.x); a0.y = fmaf(fv.x, wv.y, a0.y);
        a0.z = fmaf(fv.x, wv.z, a0.z); a0.w = fmaf(fv.x, wv.w, a0.w);
        a1.x = fmaf(fv.y, wv.x, a1.x); a1.y = fmaf(fv.y, wv.y, a1.y);
        a1.z = fmaf(fv.y, wv.z, a1.z); a1.w = fmaf(fv.y, wv.w, a1.w);
        a2.x = fmaf(fv.z, wv.x, a2.x); a2.y = fmaf(fv.z, wv.y, a2.y);
        a2.z = fmaf(fv.z, wv.z, a2.z); a2.w = fmaf(fv.z, wv.w, a2.w);
        a3.x = fmaf(fv.w, wv.x, a3.x); a3.y = fmaf(fv.w, wv.y, a3.y);
        a3.z = fmaf(fv.w, wv.z, a3.z); a3.w = fmaf(fv.w, wv.w, a3.w);
    }

    float4 accs[4] = {a0, a1, a2, a3};
    #pragma unroll
    for (int i = 0; i < 4; ++i) {
        int node = n0 + n4 + i;
        if (node < n_nodes) {
            ushort4 o;
            o.x = f2bfr(accs[i].x);
            o.y = f2bfr(accs[i].y);
            o.z = f2bfr(accs[i].z);
            o.w = f2bfr(accs[i].w);
            *reinterpret_cast<ushort4*>(g + (size_t)node * D + c4) = o;
        }
    }
}

// ---------------- bucket binning ----------------

__global__ __launch_bounds__(256) void k_bin_count(
    const int* __restrict__ dst, int* __restrict__ cnt, int n_edges, int nbkt)
{
    __shared__ int sc[1024];
    int t = threadIdx.x;
    for (int i = t; i < 1024; i += 256) sc[i] = 0;
    __syncthreads();
    int n4 = n_edges >> 2;
    const int4* d4 = (const int4*)dst;
    int stride = gridDim.x * 256;
    for (int i = blockIdx.x * 256 + t; i < n4; i += stride) {
        int4 d = d4[i];
        atomicAdd(&sc[d.x >> LOGB], 1);
        atomicAdd(&sc[d.y >> LOGB], 1);
        atomicAdd(&sc[d.z >> LOGB], 1);
        atomicAdd(&sc[d.w >> LOGB], 1);
    }
    if (blockIdx.x == 0 && t == 0)
        for (int e = n4 << 2; e < n_edges; ++e) atomicAdd(&cnt[dst[e] >> LOGB], 1);
    __syncthreads();
    for (int i = t; i < nbkt; i += 256) {
        int c = sc[i];
        if (c) atomicAdd(&cnt[i], c);
    }
}

__global__ __launch_bounds__(1024) void k_bin_scan(
    const int* __restrict__ cnt, int* __restrict__ base,
    int* __restrict__ cursor, int nbkt)
{
    int t = threadIdx.x;
    int v = (t < nbkt) ? cnt[t] : 0;
    int lane = t & 63;
    int incl = v;
    #pragma unroll
    for (int o = 1; o < 64; o <<= 1) {
        int u = __shfl_up(incl, o, 64);
        if (lane >= o) incl += u;
    }
    __shared__ int wtot[16];
    if (lane == 63) wtot[t >> 6] = incl;
    __syncthreads();
    int wpre = 0;
    int w = t >> 6;
    for (int i = 0; i < w; ++i) wpre += wtot[i];
    int excl = wpre + incl - v;
    if (t < nbkt) { base[t] = excl; cursor[t] = excl; }
    if (t == nbkt - 1) base[nbkt] = excl + v;
}

__global__ __launch_bounds__(256) void k_bin_scatter(
    const int* __restrict__ src, const int* __restrict__ dst,
    int* __restrict__ cursor, unsigned* __restrict__ packed,
    int n_edges, int sbits)
{
    __shared__ int s_cnt[1024];
    __shared__ int s_base[1024];
    __shared__ int s_gb[1024];
    __shared__ int wtot[4];
    __shared__ unsigned s_stage[4096];
    __shared__ int s_addr[4096];

    int t = threadIdx.x;
    int chbase = blockIdx.x * 4096;
    int count = n_edges - chbase;
    if (count > 4096) count = 4096;

    for (int i = t; i < 1024; i += 256) s_cnt[i] = 0;
    __syncthreads();

    #pragma unroll
    for (int k = 0; k < 16; ++k) {
        int i = t + k * 256;
        if (i < count) atomicAdd(&s_cnt[dst[chbase + i] >> LOGB], 1);
    }
    __syncthreads();

    int b4 = t * 4;
    int v0 = s_cnt[b4], v1 = s_cnt[b4 + 1], v2 = s_cnt[b4 + 2], v3 = s_cnt[b4 + 3];
    int ssum = v0 + v1 + v2 + v3;
    int lane = t & 63;
    int incl = ssum;
    #pragma unroll
    for (int o = 1; o < 64; o <<= 1) {
        int u = __shfl_up(incl, o, 64);
        if (lane >= o) incl += u;
    }
    if (lane == 63) wtot[t >> 6] = incl;
    __syncthreads();
    int wpre = 0;
    int w = t >> 6;
    for (int i = 0; i < w; ++i) wpre += wtot[i];
    int excl = wpre + incl - ssum;
    s_base[b4]     = excl;
    s_base[b4 + 1] = excl + v0;
    s_base[b4 + 2] = excl + v0 + v1;
    s_base[b4 + 3] = excl + v0 + v1 + v2;
    __syncthreads();

    for (int i = t; i < 1024; i += 256) {
        int c = s_cnt[i];
        s_gb[i] = c ? atomicAdd(&cursor[i], c) : 0;
    }
    __syncthreads();
    for (int i = t; i < 1024; i += 256) s_cnt[i] = s_base[i];
    __syncthreads();

    #pragma unroll
    for (int k = 0; k < 16; ++k) {
        int i = t + k * 256;
        if (i < count) {
            int e = chbase + i;
            int d = dst[e];
            int s = src[e];
            int bkt = d >> LOGB;
            int pos = atomicAdd(&s_cnt[bkt], 1);
            s_stage[pos] = ((unsigned)(d & (BNODES - 1)) << sbits) | (unsigned)s;
            s_addr[pos]  = s_gb[bkt] + (pos - s_base[bkt]);
        }
    }
    __syncthreads();

    #pragma unroll
    for (int k = 0; k < 16; ++k) {
        int i = t + k * 256;
        if (i < count) packed[s_addr[i]] = s_stage[i];
    }
}

// ---------------- per-sub-bucket (32 nodes): LDS sort + 4-deep segment gather ----------------
// blockIdx = bkt*4 + sub. 256 threads = 4 waves; wave owns 8 nodes. Chunk of
// the bucket's packed records staged in s_raw (1 global read), filtered+sorted
// into s_rec by node-low5; consume issues 4 gathers in flight per iteration.

__global__ __launch_bounds__(256) void k_bucket4(
    const ushort* __restrict__ g,
    const float* __restrict__ bias,
    const int* __restrict__ base,
    const unsigned* __restrict__ packed,
    float* __restrict__ out,
    int n_nodes, int sbits)
{
    __shared__ unsigned s_raw[CHUNK];     // 4 KB: raw chunk (all subs)
    __shared__ unsigned s_rec[CHUNK];     // 4 KB: this sub's sorted records
    __shared__ int s_cnt[SUBN];
    __shared__ int s_off[SUBN + 1];

    int t = threadIdx.x;
    int lane = t & 63;
    int wid  = t >> 6;                    // 0..3
    int q = lane >> 4;                    // quarter-group 0..3
    int m = lane & 15;                    // sub-lane: features 4m..4m+3
    int bkt = blockIdx.x >> 2;
    int sub = blockIdx.x & 3;
    int gb = base[bkt], ge = base[bkt + 1];
    unsigned smask = (1u << sbits) - 1u;
    const ushort* gm = g + 4 * m;

    float4 acc[8];
    int degv[8];
    #pragma unroll
    for (int k = 0; k < 8; ++k) {
        acc[k] = make_float4(0.f, 0.f, 0.f, 0.f);
        degv[k] = 0;
    }

    for (int cb = gb; cb < ge; cb += CHUNK) {
        int cnt = ge - cb;
        if (cnt > CHUNK) cnt = CHUNK;

        __syncthreads();                  // protect s_raw/s_rec from prev iter
        if (t < SUBN) s_cnt[t] = 0;
        // stage raw chunk (coalesced, single global read)
        for (int i = t; i < cnt; i += 256) s_raw[i] = packed[cb + i];
        __syncthreads();

        // histogram of this sub's records
        for (int i = t; i < cnt; i += 256) {
            unsigned key = s_raw[i] >> sbits;          // 7-bit node-low
            if ((int)(key >> 5) == sub) atomicAdd(&s_cnt[key & 31], 1);
        }
        __syncthreads();

        // exclusive scan of 32 counters (first wave) + cursor init
        if (t < 32) {
            int v = s_cnt[t];
            int incl = v;
            #pragma unroll
            for (int o = 1; o < 32; o <<= 1) {
                int u = __shfl_up(incl, o, 64);
                if (t >= o) incl += u;
            }
            int excl = incl - v;
            s_off[t] = excl;
            s_cnt[t] = excl;                           // running cursor
            if (t == 31) s_off[32] = incl;
        }
        __syncthreads();

        // scatter kept records into sorted LDS order
        for (int i = t; i < cnt; i += 256) {
            unsigned v = s_raw[i];
            unsigned key = v >> sbits;
            if ((int)(key >> 5) == sub) {
                int pos = atomicAdd(&s_cnt[key & 31], 1);
                s_rec[pos] = v;
            }
        }
        __syncthreads();

        // consume: wave wid owns nodes r = wid*8 .. +7; 4 gathers in flight
        #pragma unroll
        for (int k = 0; k < 8; ++k) {
            int r = wid * 8 + k;
            int beg = s_off[r], end = s_off[r + 1];
            float4 a = acc[k];
            for (int i = beg; i < end; i += 16) {
                int i0 = i + q, i1 = i0 + 4, i2 = i0 + 8, i3 = i0 + 12;
                bool p0 = i0 < end, p1 = i1 < end, p2 = i2 < end, p3 = i3 < end;
                unsigned r0 = s_rec[p0 ? i0 : beg];
                unsigned r1 = s_rec[p1 ? i1 : beg];
                unsigned r2 = s_rec[p2 ? i2 : beg];
                unsigned r3 = s_rec[p3 ? i3 : beg];
                int s0 = (int)(r0 & smask), s1 = (int)(r1 & smask);
                int s2 = (int)(r2 & smask), s3 = (int)(r3 & smask);
                uint2 u0 = *reinterpret_cast<const uint2*>(gm + (size_t)s0 * D);
                uint2 u1 = *reinterpret_cast<const uint2*>(gm + (size_t)s1 * D);
                uint2 u2 = *reinterpret_cast<const uint2*>(gm + (size_t)s2 * D);
                uint2 u3 = *reinterpret_cast<const uint2*>(gm + (size_t)s3 * D);
                a.x += p0 ? blo(u0.x) : 0.0f;  a.y += p0 ? bhi(u0.x) : 0.0f;
                a.z += p0 ? blo(u0.y) : 0.0f;  a.w += p0 ? bhi(u0.y) : 0.0f;
                a.x += p1 ? blo(u1.x) : 0.0f;  a.y += p1 ? bhi(u1.x) : 0.0f;
                a.z += p1 ? blo(u1.y) : 0.0f;  a.w += p1 ? bhi(u1.y) : 0.0f;
                a.x += p2 ? blo(u2.x) : 0.0f;  a.y += p2 ? bhi(u2.x) : 0.0f;
                a.z += p2 ? blo(u2.y) : 0.0f;  a.w += p2 ? bhi(u2.y) : 0.0f;
                a.x += p3 ? blo(u3.x) : 0.0f;  a.y += p3 ? bhi(u3.x) : 0.0f;
                a.z += p3 ? blo(u3.y) : 0.0f;  a.w += p3 ? bhi(u3.y) : 0.0f;
            }
            acc[k] = a;
            degv[k] += end - beg;
        }
    }

    // epilogue: cross-quarter reduce, mean / deg-0 fallback, +bias, ReLU
    float4 bj = *reinterpret_cast<const float4*>(bias + 4 * m);
    int n0 = (bkt << LOGB) + sub * SUBN;
    #pragma unroll
    for (int k = 0; k < 8; ++k) {
        float4 v = acc[k];
        v.x += __shfl_xor(v.x, 16, 64);
        v.y += __shfl_xor(v.y, 16, 64);
        v.z += __shfl_xor(v.z, 16, 64);
        v.w += __shfl_xor(v.w, 16, 64);
        v.x += __shfl_xor(v.x, 32, 64);
        v.y += __shfl_xor(v.y, 32, 64);
        v.z += __shfl_xor(v.z, 32, 64);
        v.w += __shfl_xor(v.w, 32, 64);
        if ((k & 3) == q) {
            int node = n0 + wid * 8 + k;
            if (node < n_nodes) {
                int dgt = degv[k];
                float4 res;
                if (dgt > 0) {
                    float inv = 1.0f / (float)dgt;
                    res = make_float4(v.x * inv, v.y * inv, v.z * inv, v.w * inv);
                } else {
                    uint2 u = *reinterpret_cast<const uint2*>(gm + (size_t)node * D);
                    res = make_float4(blo(u.x), bhi(u.x), blo(u.y), bhi(u.y));
                }
                res.x = fmaxf(res.x + bj.x, 0.0f);
                res.y = fmaxf(res.y + bj.y, 0.0f);
                res.z = fmaxf(res.z + bj.z, 0.0f);
                res.w = fmaxf(res.w + bj.w, 0.0f);
                *reinterpret_cast<float4*>(out + (size_t)node * D + 4 * m) = res;
            }
        }
    }
}

// ---------------- fallback: R3 CSR path ----------------

__global__ __launch_bounds__(256) void k_hist(
    const int* __restrict__ dst, int* __restrict__ cnt, int n_edges)
{
    int n4 = n_edges >> 2;
    const int4* d4 = (const int4*)dst;
    int stride = gridDim.x * blockDim.x;
    for (int i = blockIdx.x * blockDim.x + threadIdx.x; i < n4; i += stride) {
        int4 d = d4[i];
        atomicAdd(&cnt[d.x], 1); atomicAdd(&cnt[d.y], 1);
        atomicAdd(&cnt[d.z], 1); atomicAdd(&cnt[d.w], 1);
    }
    if (blockIdx.x == 0 && threadIdx.x == 0)
        for (int e = n4 << 2; e < n_edges; ++e) atomicAdd(&cnt[dst[e]], 1);
}

__global__ __launch_bounds__(256) void k_scan1(
    const int* __restrict__ cnt, int* __restrict__ off,
    int* __restrict__ bsum, int n)
{
    int t = threadIdx.x, b = blockIdx.x;
    int base = b * 1024 + t * 4;
    int v0 = (base + 0 < n) ? cnt[base + 0] : 0;
    int v1 = (base + 1 < n) ? cnt[base + 1] : 0;
    int v2 = (base + 2 < n) ? cnt[base + 2] : 0;
    int v3 = (base + 3 < n) ? cnt[base + 3] : 0;
    int s = v0 + v1 + v2 + v3;
    int lane = t & 63;
    int incl = s;
    #pragma unroll
    for (int o = 1; o < 64; o <<= 1) {
        int u = __shfl_up(incl, o, 64);
        if (lane >= o) incl += u;
    }
    __shared__ int wtot[4];
    if (lane == 63) wtot[t >> 6] = incl;
    __syncthreads();
    int w = t >> 6;
    int wpre = 0;
    for (int i = 0; i < w; ++i) wpre += wtot[i];
    int excl = wpre + incl - s;
    int p0 = excl + v0, p1 = p0 + v1, p2 = p1 + v2, p3 = p2 + v3;
    if (base + 0 < n) off[base + 1] = p0;
    if (base + 1 < n) off[base + 2] = p1;
    if (base + 2 < n) off[base + 3] = p2;
    if (base + 3 < n) off[base + 4] = p3;
    if (t == 255) bsum[b] = wpre + incl;
}

__global__ __launch_bounds__(128) void k_scan2(int* __restrict__ bsum, int nb)
{
    int t = threadIdx.x;
    int v = (t < nb) ? bsum[t] : 0;
    int lane = t & 63;
    int incl = v;
    #pragma unroll
    for (int o = 1; o < 64; o <<= 1) {
        int u = __shfl_up(incl, o, 64);
        if (lane >= o) incl += u;
    }
    __shared__ int wt[2];
    if (lane == 63) wt[t >> 6] = incl;
    __syncthreads();
    int add = (t >> 6) ? wt[0] : 0;
    if (t < nb) bsum[t] = add + incl - v;
}

__global__ __launch_bounds__(256) void k_scan3(
    int* __restrict__ off, int* __restrict__ cursor,
    const int* __restrict__ bsum, int n)
{
    int t = threadIdx.x, b = blockIdx.x;
    int base = b * 1024 + t * 4;
    int add = bsum[b];
    #pragma unroll
    for (int i = 0; i < 4; ++i) {
        int idx = base + i;
        if (idx < n) {
            int v = off[idx + 1] + add;
            off[idx + 1] = v;
            if (idx + 1 < n) cursor[idx + 1] = v;
        }
    }
    if (b == 0 && t == 0) { off[0] = 0; cursor[0] = 0; }
}

__global__ __launch_bounds__(256) void k_scatter_csr(
    const int* __restrict__ src, const int* __restrict__ dst,
    int* __restrict__ cursor, int* __restrict__ csr, int n_edges)
{
    int n4 = n_edges >> 2;
    const int4* s4 = (const int4*)src;
    const int4* d4 = (const int4*)dst;
    int stride = gridDim.x * blockDim.x;
    for (int i = blockIdx.x * blockDim.x + threadIdx.x; i < n4; i += stride) {
        int4 s = s4[i];
        int4 d = d4[i];
        csr[atomicAdd(&cursor[d.x], 1)] = s.x;
        csr[atomicAdd(&cursor[d.y], 1)] = s.y;
        csr[atomicAdd(&cursor[d.z], 1)] = s.z;
        csr[atomicAdd(&cursor[d.w], 1)] = s.w;
    }
    if (blockIdx.x == 0 && threadIdx.x == 0)
        for (int e = n4 << 2; e < n_edges; ++e)
            csr[atomicAdd(&cursor[dst[e]], 1)] = src[e];
}

__global__ __launch_bounds__(256) void k_node(
    const float* __restrict__ feat, const float* __restrict__ W,
    const float* __restrict__ bias, const int* __restrict__ off,
    const int* __restrict__ csr, float* __restrict__ out, int n_nodes)
{
    __shared__ float Wl[D * D];
    int tid = threadIdx.x;
    for (int i = tid; i < D * D; i += 256) Wl[i] = W[i];
    __syncthreads();
    int lane = tid & 63, wid = tid >> 6;
    float bj = bias[lane];
    int nwaves = gridDim.x * 4;
    for (int n = blockIdx.x * 4 + wid; n < n_nodes; n += nwaves) {
        int beg = off[n], end = off[n + 1];
        float acc = 0.0f;
        int i = beg;
        for (; i + 4 <= end; i += 4) {
            int s0 = csr[i], s1 = csr[i + 1], s2 = csr[i + 2], s3 = csr[i + 3];
            acc += feat[s0 * D + lane] + feat[s1 * D + lane]
                 + feat[s2 * D + lane] + feat[s3 * D + lane];
        }
        for (; i < end; ++i) acc += feat[csr[i] * D + lane];
        int dg = end - beg;
        float h = (dg > 0) ? (acc / (float)dg) : feat[n * D + lane];
        float o = bj;
        #pragma unroll
        for (int k = 0; k < D; ++k)
            o = fmaf(__shfl(h, k, 64), Wl[k * D + lane], o);
        out[n * D + lane] = fmaxf(o, 0.0f);
    }
}

// ---------------- host ----------------

extern "C" void kernel_launch(void* const* d_in, const int* in_sizes, int n_in,
                              void* d_out, int out_size, void* d_ws, size_t ws_size,
                              hipStream_t stream)
{
    const float* feat = (const float*)d_in[0];
    const int*   src  = (const int*)d_in[1];
    const int*   dst  = (const int*)d_in[2];
    const float* W    = (const float*)d_in[3];
    const float* b    = (const float*)d_in[4];
    float* out = (float*)d_out;

    int n_nodes = in_sizes[0] / D;
    int n_edges = in_sizes[1];
    int nbkt = (n_nodes + BNODES - 1) >> LOGB;

    int sbits = 1;
    while ((1 << sbits) < n_nodes && sbits < 26) sbits++;

    // ws layout: base[nbkt+1] | cnt[nbkt] | cursor[nbkt] | packed[E] u32 | g[N*D] u16
    size_t base_off   = 0;
    size_t cnt_off    = (((size_t)(nbkt + 1) * 4) + 63) & ~(size_t)63;
    size_t cursor_off = (cnt_off + (size_t)nbkt * 4 + 63) & ~(size_t)63;
    size_t packed_off = (cursor_off + (size_t)nbkt * 4 + 63) & ~(size_t)63;
    size_t g_off      = (packed_off + (size_t)n_edges * 4 + 63) & ~(size_t)63;
    size_t need_new   = g_off + (size_t)n_nodes * D * 2;

    bool new_ok = (ws_size >= need_new) && (nbkt <= 1024) &&
                  (sbits + LOGB <= 32) && ((1 << sbits) >= n_nodes);

    if (new_ok) {
        char* ws = (char*)d_ws;
        int* bbase   = (int*)(ws + base_off);
        int* bcnt    = (int*)(ws + cnt_off);
        int* bcursor = (int*)(ws + cursor_off);
        unsigned* packed = (unsigned*)(ws + packed_off);
        ushort* g    = (ushort*)(ws + g_off);

        int tblk = (n_nodes + TN - 1) / TN;
        k_transform3<<<tblk, 256, 0, stream>>>(feat, W, g, n_nodes, bcnt, nbkt);
        k_bin_count<<<512, 256, 0, stream>>>(dst, bcnt, n_edges, nbkt);
        k_bin_scan<<<1, 1024, 0, stream>>>(bcnt, bbase, bcursor, nbkt);
        int nblk = (n_edges + 4095) / 4096;
        k_bin_scatter<<<nblk, 256, 0, stream>>>(src, dst, bcursor, packed,
                                                n_edges, sbits);
        k_bucket4<<<nbkt * 4, 256, 0, stream>>>(g, b, bbase, packed, out,
                                                n_nodes, sbits);
    } else {
        // R3 CSR fallback
        int nb = (n_nodes + 1023) / 1024;
        size_t c_off  = 0;
        size_t o_off  = (((size_t)n_nodes * 4) + 63) & ~(size_t)63;
        size_t bs_off = (o_off + ((size_t)n_nodes + 1) * 4 + 63) & ~(size_t)63;
        size_t cs_off = (bs_off + 128 * 4 + 63) & ~(size_t)63;
        char* ws = (char*)d_ws;
        int* cnt  = (int*)(ws + c_off);
        int* off  = (int*)(ws + o_off);
        int* bsum = (int*)(ws + bs_off);
        int* csr  = (int*)(ws + cs_off);

        hipMemsetAsync(cnt, 0, (size_t)n_nodes * 4, stream);
        k_hist<<<2048, 256, 0, stream>>>(dst, cnt, n_edges);
        k_scan1<<<nb, 256, 0, stream>>>(cnt, off, bsum, n_nodes);
        k_scan2<<<1, 128, 0, stream>>>(bsum, nb);
        k_scan3<<<nb, 256, 0, stream>>>(off, cnt, bsum, n_nodes);
        k_scatter_csr<<<2048, 256, 0, stream>>>(src, dst, cnt, csr, n_edges);
        k_node<<<2048, 256, 0, stream>>>(feat, W, b, off, csr, out, n_nodes);
    }
}